// Round 1
// baseline (695.829 us; speedup 1.0000x reference)
//
#include <hip/hip_runtime.h>

// ConfusionAwareFocalLoss: N=1048576 rows, C=128 classes, gamma=2, smoothing=0.1
// loss_i = cw[t] * sum_j -(1-p_j)^2 * (0.1/128 + 0.9*[j==t]) * logp_j
//        + sum_j max(P[t,j]-1, 0) * p_j          (P diag == 1 -> term 0)
// out = mean_i loss_i
//
// R1: latency-bound theory. 4 rows/wave/iter (16 lanes x 8 elems), one 4-step
// shuffle chain reduces all 4 rows; manual prefetch of next iteration's inputs
// + targets; nontemporal input loads. Goal: raise MLP toward the 6.3 TB/s ceiling.

#define NROWS 1048576
#define NCLS  128
#define BLOCK 256
#define GRID  4096

#define WPB    (BLOCK / 64)          // waves per block = 4
#define NWAVES (GRID * WPB)          // 16384
#define NQUADS (NROWS / 4)           // 262144 (4 rows per wave-iteration)
#define QPW    (NQUADS / NWAVES)     // 16 iterations per wave, exact

constexpr float SMOOTH_OFF = 0.1f / 128.0f;
constexpr float SMOOTH_ON  = 0.9f;   // extra weight on the target column

using f4 = __attribute__((ext_vector_type(4))) float;

__global__ __launch_bounds__(BLOCK) void focal_main(
    const float* __restrict__ inputs,     // [N, 128]
    const int*   __restrict__ targets,    // [N]
    const float* __restrict__ cls_w,      // [128]
    const float* __restrict__ P,          // [128, 128]
    float*       __restrict__ partial)    // [GRID]
{
    const int tid  = threadIdx.x;
    const int lane = tid & 63;
    const int wib  = tid >> 6;            // wave in block (0..3)
    const int g    = lane >> 4;           // row within quad (0..3)
    const int q16  = lane & 15;           // position within 16-lane row-group
    const int jb   = q16 * 8;             // first class index this lane owns

    const int waveId = blockIdx.x * WPB + wib;
    const f4* in4 = reinterpret_cast<const f4*>(inputs);

    // quad layout: rows [quad*4 .. quad*4+3]; flat float idx = quad*512 + lane*8
    // -> f4 idx = quad*128 + lane*2 (+1). Wave covers 2 KiB contiguous per iter.
    int q = waveId * QPW;

    // prefetch iteration 0
    f4 A = __builtin_nontemporal_load(in4 + (size_t)q * 128 + lane * 2);
    f4 B = __builtin_nontemporal_load(in4 + (size_t)q * 128 + lane * 2 + 1);
    int t = targets[q * 4 + g];

    float acc = 0.0f;

    for (int it = 0; it < QPW; ++it) {
        // ---- prefetch next iteration (wave-uniform index, clamped in-range) ----
        int qn = q + 1;
        if (qn >= NQUADS) qn = 0;         // last iter: harmless dummy prefetch
        const f4 An = __builtin_nontemporal_load(in4 + (size_t)qn * 128 + lane * 2);
        const f4 Bn = __builtin_nontemporal_load(in4 + (size_t)qn * 128 + lane * 2 + 1);
        const int tn = targets[qn * 4 + g];

        // ---- scattered (cache-resident) per-target loads for CURRENT iter ----
        const float cw = cls_w[t];
        const f4* prow = reinterpret_cast<const f4*>(P + (size_t)t * NCLS);
        const f4 pa = prow[q16 * 2];
        const f4 pb = prow[q16 * 2 + 1];

        // ---- row max over 128 elems = 16 lanes x 8; one chain does 4 rows ----
        float m = fmaxf(fmaxf(fmaxf(A[0], A[1]), fmaxf(A[2], A[3])),
                        fmaxf(fmaxf(B[0], B[1]), fmaxf(B[2], B[3])));
        #pragma unroll
        for (int off = 8; off > 0; off >>= 1)
            m = fmaxf(m, __shfl_xor(m, off, 64));

        float ev[8];
        #pragma unroll
        for (int k = 0; k < 4; ++k) ev[k]     = __expf(A[k] - m);
        #pragma unroll
        for (int k = 0; k < 4; ++k) ev[4 + k] = __expf(B[k] - m);

        float z = ((ev[0] + ev[1]) + (ev[2] + ev[3]))
                + ((ev[4] + ev[5]) + (ev[6] + ev[7]));
        #pragma unroll
        for (int off = 8; off > 0; off >>= 1)
            z += __shfl_xor(z, off, 64);

        const float mlz = m + __logf(z);  // x - mlz = log_softmax
        const float rZ  = 1.0f / z;

        float s1 = 0.0f, te = 0.0f, pen = 0.0f;
        #pragma unroll
        for (int k = 0; k < 8; ++k) {
            const float x   = (k < 4) ? A[k] : B[k - 4];
            const float pvk = (k < 4) ? pa[k] : pb[k - 4];
            const float lp  = x - mlz;           // log prob
            const float p   = ev[k] * rZ;        // prob
            const float om  = 1.0f - p;
            const float fw  = om * om;           // focal weight, gamma=2
            const float fl  = fw * lp;
            s1 += fl;                            // sum_j fw*lp
            if (jb + k == t) te = fl;            // target column's fw*lp
            pen += fmaxf(pvk - 1.0f, 0.0f) * p;  // confusion penalty
        }
        // base = -(SMOOTH_OFF*s1 + SMOOTH_ON*te); loss = cw*base + pen
        acc += pen - cw * (SMOOTH_OFF * s1 + SMOOTH_ON * te);

        A = An; B = Bn; t = tn; q = qn;
    }

    // full-wave reduce (rows fully folded already; mixing lanes is fine now)
    #pragma unroll
    for (int off = 32; off > 0; off >>= 1)
        acc += __shfl_xor(acc, off, 64);

    __shared__ float ssum[WPB];
    if (lane == 0) ssum[wib] = acc;
    __syncthreads();
    if (tid == 0) {
        float s = 0.0f;
        #pragma unroll
        for (int w = 0; w < WPB; ++w) s += ssum[w];
        partial[blockIdx.x] = s;
    }
}

__global__ __launch_bounds__(256) void focal_final(
    const float* __restrict__ partial, float* __restrict__ out)
{
    double s = 0.0;
    for (int i = threadIdx.x; i < GRID; i += 256) s += (double)partial[i];

    #pragma unroll
    for (int off = 32; off > 0; off >>= 1)
        s += __shfl_xor(s, off, 64);

    __shared__ double sh[4];
    const int wave = threadIdx.x >> 6;
    if ((threadIdx.x & 63) == 0) sh[wave] = s;
    __syncthreads();
    if (threadIdx.x == 0) {
        double tot = sh[0] + sh[1] + sh[2] + sh[3];
        out[0] = (float)(tot / (double)NROWS);
    }
}

extern "C" void kernel_launch(void* const* d_in, const int* in_sizes, int n_in,
                              void* d_out, int out_size, void* d_ws, size_t ws_size,
                              hipStream_t stream) {
    const float* inputs  = (const float*)d_in[0];
    const int*   targets = (const int*)  d_in[1];
    const float* cls_w   = (const float*)d_in[2];
    const float* P       = (const float*)d_in[3];
    float* out     = (float*)d_out;
    float* partial = (float*)d_ws;   // GRID floats = 16 KiB

    focal_main<<<GRID, BLOCK, 0, stream>>>(inputs, targets, cls_w, P, partial);
    focal_final<<<1, 256, 0, stream>>>(partial, out);
}